// Round 1
// baseline (615.842 us; speedup 1.0000x reference)
//
#include <hip/hip_runtime.h>
#include <math.h>

// SparseNet: conv1(2x2,200->16,pad(0,1)) * mask -> maskedpool 3x3/3 ->
// conv2(5x5,16->32,VALID) * pooledmask -> maskedpool 3x3/1 -> linear(32,2) -> softmax
// B=1024, H=W=21, Cin=200.

#define NEGINF -1e30f

// ---------------- Kernel A: conv1 + mask + masked maxpool (21 -> 7) ----------------
// grid = 1024 (one block per batch), block = 256.
// Writes h2 [1024][49][16] and m2 [1024][49] to workspace.
__global__ __launch_bounds__(256) void conv1_pool_kernel(
    const float* __restrict__ x,     // [1024,21,21,200]
    const int*   __restrict__ mask,  // [1024,21,21]
    const float* __restrict__ W1,    // [2,2,200,16]
    float* __restrict__ h2,          // [1024,49,16]
    float* __restrict__ m2)          // [1024,49]
{
    __shared__ float h1s[441][16];   // conv1 output (only active sites written)

    const int b = blockIdx.x;
    const int t = threadIdx.x;
    const int* __restrict__ mb = mask + b * 441;
    const float* __restrict__ xb = x + (size_t)b * 441 * 200;

    // ---- conv1 at active output pixels ----
    for (int p = t; p < 441; p += 256) {
        if (mb[p] == 0) continue;          // output site inactive -> h1*m == 0, pool ignores it
        const int i = p / 21;
        const int j = p - i * 21;

        float acc[16];
        #pragma unroll
        for (int c = 0; c < 16; ++c) acc[c] = 0.0f;

        #pragma unroll
        for (int tap = 0; tap < 4; ++tap) {
            const int di = tap >> 1, dj = tap & 1;
            const int ii = i + di, jj = j + dj;
            // pad (0,1): ii==21 or jj==21 is zero padding; inactive taps contribute 0
            if (ii < 21 && jj < 21 && mb[ii * 21 + jj] != 0) {
                const float4* __restrict__ xp =
                    (const float4*)(xb + (ii * 21 + jj) * 200);
                const float4* __restrict__ wp =
                    (const float4*)(W1 + tap * 200 * 16);  // wave-uniform address stream

                #pragma unroll 2
                for (int k4 = 0; k4 < 50; ++k4) {
                    const float4 xv = xp[k4];
                    const float xs0 = xv.x, xs1 = xv.y, xs2 = xv.z, xs3 = xv.w;
                    #pragma unroll
                    for (int u = 0; u < 4; ++u) {
                        const float xs = (u == 0) ? xs0 : (u == 1) ? xs1 : (u == 2) ? xs2 : xs3;
                        const int k = k4 * 4 + u;
                        const float4 w0 = wp[k * 4 + 0];
                        const float4 w1 = wp[k * 4 + 1];
                        const float4 w2 = wp[k * 4 + 2];
                        const float4 w3 = wp[k * 4 + 3];
                        acc[0]  = fmaf(xs, w0.x, acc[0]);
                        acc[1]  = fmaf(xs, w0.y, acc[1]);
                        acc[2]  = fmaf(xs, w0.z, acc[2]);
                        acc[3]  = fmaf(xs, w0.w, acc[3]);
                        acc[4]  = fmaf(xs, w1.x, acc[4]);
                        acc[5]  = fmaf(xs, w1.y, acc[5]);
                        acc[6]  = fmaf(xs, w1.z, acc[6]);
                        acc[7]  = fmaf(xs, w1.w, acc[7]);
                        acc[8]  = fmaf(xs, w2.x, acc[8]);
                        acc[9]  = fmaf(xs, w2.y, acc[9]);
                        acc[10] = fmaf(xs, w2.z, acc[10]);
                        acc[11] = fmaf(xs, w2.w, acc[11]);
                        acc[12] = fmaf(xs, w3.x, acc[12]);
                        acc[13] = fmaf(xs, w3.y, acc[13]);
                        acc[14] = fmaf(xs, w3.z, acc[14]);
                        acc[15] = fmaf(xs, w3.w, acc[15]);
                    }
                }
            }
        }
        #pragma unroll
        for (int c = 0; c < 16; ++c) h1s[p][c] = acc[c];
    }

    __syncthreads();

    // ---- masked maxpool 3x3 stride 3: 21x21 -> 7x7 ----
    for (int t2 = t; t2 < 784; t2 += 256) {
        const int cell = t2 >> 4;        // 0..48
        const int ch   = t2 & 15;
        const int pr = cell / 7, pc = cell - pr * 7;
        float best = NEGINF;
        bool any = false;
        #pragma unroll
        for (int r = 0; r < 3; ++r) {
            #pragma unroll
            for (int c = 0; c < 3; ++c) {
                const int si = pr * 3 + r, sj = pc * 3 + c;
                if (mb[si * 21 + sj] != 0) {
                    any = true;
                    best = fmaxf(best, h1s[si * 21 + sj][ch]);
                }
            }
        }
        h2[(size_t)(b * 49 + cell) * 16 + ch] = any ? best : 0.0f;
        if (ch == 0) m2[b * 49 + cell] = any ? 1.0f : 0.0f;
    }
}

// ---------------- Kernel B: conv2 + mask + final masked pool + linear + softmax ----------------
// grid = 1024, block = 256.
__global__ __launch_bounds__(256) void tail_kernel(
    const float* __restrict__ h2,    // [1024,49,16]
    const float* __restrict__ m2,    // [1024,49]
    const float* __restrict__ W2,    // [5,5,16,32]
    const float* __restrict__ Wlin,  // [32,2]
    const float* __restrict__ blin,  // [2]
    float* __restrict__ out)         // [1024,2]
{
    __shared__ float h2s[49][16];
    __shared__ float m2s[49];
    __shared__ float hc[9][32];
    __shared__ float m3s[9];
    __shared__ float h4[32];

    const int b = blockIdx.x;
    const int t = threadIdx.x;

    for (int t2 = t; t2 < 784; t2 += 256)
        h2s[t2 >> 4][t2 & 15] = h2[(size_t)b * 784 + t2];
    if (t < 49) m2s[t] = m2[b * 49 + t];
    __syncthreads();

    // conv2: 7x7 -> 3x3, 16 -> 32 channels; gate by 5x5 mask-pool
    for (int t2 = t; t2 < 288; t2 += 256) {
        const int cell = t2 >> 5;        // 0..8
        const int oc   = t2 & 31;
        const int ci = cell / 3, cj = cell - ci * 3;
        float acc = 0.0f;
        float mm = 0.0f;
        #pragma unroll
        for (int di = 0; di < 5; ++di) {
            #pragma unroll
            for (int dj = 0; dj < 5; ++dj) {
                const int s = (ci + di) * 7 + (cj + dj);
                mm = fmaxf(mm, m2s[s]);
                const float* __restrict__ wrow = W2 + ((di * 5 + dj) * 16) * 32 + oc;
                #pragma unroll
                for (int c = 0; c < 16; ++c)
                    acc = fmaf(h2s[s][c], wrow[c * 32], acc);
            }
        }
        hc[cell][oc] = (mm > 0.0f) ? acc : 0.0f;
        if (oc == 0) m3s[cell] = mm;
    }
    __syncthreads();

    // final masked maxpool 3x3 stride 1 on 3x3 -> 1x1 (window covers all 9 cells)
    if (t < 32) {
        float best = NEGINF;
        bool any = false;
        #pragma unroll
        for (int cell = 0; cell < 9; ++cell) {
            if (m3s[cell] > 0.0f) {
                any = true;
                best = fmaxf(best, hc[cell][t]);
            }
        }
        h4[t] = any ? best : 0.0f;
    }
    __syncthreads();

    if (t == 0) {
        float l0 = blin[0], l1 = blin[1];
        #pragma unroll
        for (int c = 0; c < 32; ++c) {
            l0 = fmaf(h4[c], Wlin[c * 2 + 0], l0);
            l1 = fmaf(h4[c], Wlin[c * 2 + 1], l1);
        }
        const float mx = fmaxf(l0, l1);
        const float e0 = expf(l0 - mx);
        const float e1 = expf(l1 - mx);
        const float inv = 1.0f / (e0 + e1);
        out[b * 2 + 0] = e0 * inv;
        out[b * 2 + 1] = e1 * inv;
    }
}

extern "C" void kernel_launch(void* const* d_in, const int* in_sizes, int n_in,
                              void* d_out, int out_size, void* d_ws, size_t ws_size,
                              hipStream_t stream) {
    const float* x    = (const float*)d_in[0];
    const int*   mask = (const int*)d_in[1];
    const float* W1   = (const float*)d_in[2];
    const float* W2   = (const float*)d_in[3];
    const float* Wlin = (const float*)d_in[4];
    const float* blin = (const float*)d_in[5];
    float* out = (float*)d_out;

    float* h2 = (float*)d_ws;                  // 1024*49*16 floats = 3.21 MB
    float* m2 = h2 + 1024 * 49 * 16;           // 1024*49 floats

    conv1_pool_kernel<<<1024, 256, 0, stream>>>(x, mask, W1, h2, m2);
    tail_kernel<<<1024, 256, 0, stream>>>(h2, m2, W2, Wlin, blin, out);
}